// Round 2
// 192.300 us; speedup vs baseline: 1.1104x; 1.1104x over previous
//
#include <hip/hip_runtime.h>
#include <hip/hip_fp16.h>
#include <math.h>

#define B_    32
#define F_    4000
#define L_    65
#define N_    129           // 2L-1, odd irfft length
#define HOP_  64
#define K_    192           // hop + 2L - 2
#define GF_   8             // frames per wave
#define WAVES_ 4
#define OUTLEN_ ((F_-1)*HOP_ + K_)   // 256128
#define GAIN_ 0.01f
#define BLKS_PER_B_ (F_/(GF_*WAVES_))   // 125
#define CPH_  260           // halves per copy (positions 0..259, zero-padded)

// R10 delta vs R9 (attack the measured bottleneck): counters show VALU-issue
// bound (VALUBusy 77%, HBM 8%, Mfma 0, DS ~53%). Halve VALU issue:
//  - Phase B: v_dot2_f32_f16 (2 f16 MACs, f32 accum). Taps in LDS already have
//    the (j=2p+1 lo, j=2p hi) dword layout dot2 needs; z is pre-packed to f16
//    pairs once per frame (2 ds_bpermute + cvt_pkrtz), so per pair:
//    1 readlane + 3 dot2 (was 2 readlane + 6 fma_mix).
//  - Phase A: stride-2 Chebyshev, odd/even-k subchains packed into
//    v_pk_fma_f32 (full rate). Coefficient pairs (X[2q+1],X[2q+2]) are
//    memory-adjacent -> even-aligned SGPR pair operand for VOP3P.
// Precision: f16 z adds ~6e-6 (RTZ, center tap 0.5 x 2^-10 x GAIN); Phase A
// unchanged f32 math with SHORTER recurrence chains. launch_bounds(256,3)
// pins the 85-VGPR / 3-waves-per-SIMD budget we relied on implicitly before.
// R11: fix compile error — cvt_pkrtz returns __fp16x2, bit_cast to h2f.

typedef float    v2f __attribute__((ext_vector_type(2)));
typedef _Float16 h2f __attribute__((ext_vector_type(2)));

static __device__ __forceinline__ v2f pk_fma(v2f a, v2f b, v2f c) {
#if __has_builtin(__builtin_elementwise_fma)
    return __builtin_elementwise_fma(a, b, c);
#else
    return a * b + c;
#endif
}

#if __has_builtin(__builtin_amdgcn_fdot2)
#define FDOT2(a, b, c) __builtin_amdgcn_fdot2((a), (b), (c), false)
#else
static __device__ __forceinline__ float fdot2_sw(h2f a, h2f b, float c) {
    return fmaf((float)a.x, (float)b.x, fmaf((float)a.y, (float)b.y, c));
}
#define FDOT2(a, b, c) fdot2_sw((a), (b), (c))
#endif

__global__ __launch_bounds__(256, 3) void filtered_noise_kernel(
    const float* __restrict__ nfilt,   // [B,F,65]
    const float* __restrict__ noise,   // [B,F,64]
    float* __restrict__ out)           // [B, OUTLEN]
{
    __shared__ float costab[N_];
    __shared__ __half hbuf[WAVES_][2][CPH_];  // [copyE(+64), copyO(+65)] per wave

    const int tid  = threadIdx.x;
    const int lane = tid & 63;
    const int wid  = __builtin_amdgcn_readfirstlane(tid >> 6);

    for (int i = tid; i < N_; i += 256)
        costab[i] = (float)cos((double)i * (2.0 * M_PI / 129.0));

    __half* hb = &hbuf[wid][0][0];
    for (int i = lane; i < 2 * CPH_; i += 64) hb[i] = __float2half(0.0f);

    __syncthreads();   // costab + zero init; the only block barrier

    const int b  = blockIdx.x / BLKS_PER_B_;
    const int g  = (blockIdx.x % BLKS_PER_B_) * WAVES_ + wid;  // group in [0,500)
    const int f0 = g * GF_;

    const int   t     = lane + 1;            // lane computes ir_raw[t], t=1..64
    const float scale = 2.0f / 129.0f;
    const float cA = 0.5f * (1.0f - costab[64 - t]) * scale;   // win[64-t]*(2/129)
    const float cB = 0.5f * (1.0f - costab[64 + t]) * scale;   // win[64+t]*(2/129)
    const float c0 = 0.5f * (1.0f - costab[64]) * scale;       // win[64]  *(2/129)

    // stride-2 packed Chebyshev constants/seeds (exact table values)
    const float c1t = costab[t];                 // cos(t*th)
    const float c2t = costab[(2 * t) % N_];      // cos(2t*th)
    const float tc2 = 2.0f * c2t;                // stride-2 recurrence constant
    const v2f sck1  = {costab[(33 * t) % N_], costab[(34 * t) % N_]};
    const v2f sckm1 = {costab[(31 * t) % N_], costab[(32 * t) % N_]};

    const float* Xf = nfilt + (size_t)(b * F_ + f0) * L_;          // uniform
    const float* Zf = noise + (size_t)(b * F_ + f0) * HOP_ + lane; // per-lane
    float*       op = out + (size_t)b * OUTLEN_ + (size_t)f0 * HOP_ + lane;

    __half* hE = &hbuf[wid][0][0];   // tap m at pos m+64
    __half* hO = &hbuf[wid][1][0];   // tap m at pos m+65

    // Per-lane read base: odd lanes use copyE (shift 0), even lanes copyO (+1)
    // so every j-pair dword is aligned with uniform half->j mapping.
    const int soff = (lane & 1) ? 0 : 1;
    const __half* cpsel = (lane & 1) ? hE : hO;
    const h2f* bmin = (const h2f*)cpsel + (((lane + soff + 63) >> 1) - 31);
    // seg s, pair p: dword = bmin[(31-p) + 32*s]; low half = tap(j=2p+1), high = tap(j=2p)

    // rolling accumulators, 2 partial chains each (pair parity)
    float wa[2] = {0,0}, wb[2] = {0,0}, wc[2] = {0,0};

    #pragma unroll 1
    for (int i = 0; i < GF_; ++i) {
        // coalesced per-lane noise load (vmcnt; hidden behind Phase A)
        float zc = Zf[0];
        zc = fmaf(2.0f, zc, -1.0f);

        // ---- Phase A: a = 0.5*X0 + sum_{k=1..64} X[k]*cos(k*t*th) ----
        // packed stride-2 Chebyshev: lo half = odd-k subchain, hi = even-k.
        v2f aa0 = {0.0f, 0.0f}, aa1 = {0.0f, 0.0f}, ssv = {0.0f, 0.0f};
        v2f ck0 = {c1t, c2t};        // {cos(1*t*th), cos(2*t*th)}
        v2f km0 = {c1t, 1.0f};       // {cos(-1*t*th), cos(0)}
        v2f ck1 = sck1;              // {cos(33*t*th), cos(34*t*th)}
        v2f km1 = sckm1;             // {cos(31*t*th), cos(32*t*th)}
        const v2f tcv = {tc2, tc2};
        #pragma unroll
        for (int q = 0; q < 16; ++q) {
            v2f x0 = { Xf[2*q + 1],  Xf[2*q + 2]  };   // adjacent uniform loads
            v2f x1 = { Xf[2*q + 33], Xf[2*q + 34] };
            aa0 = pk_fma(x0, ck0, aa0);
            aa1 = pk_fma(x1, ck1, aa1);
            ssv = ssv + x0 + x1;
            v2f n0 = pk_fma(tcv, ck0, -km0);   // cos((k+2)*t*th)
            v2f n1 = pk_fma(tcv, ck1, -km1);
            km0 = ck0; ck0 = n0;
            km1 = ck1; ck1 = n1;
        }
        float x0s = Xf[0];
        float a = 0.5f * x0s + (aa0.x + aa0.y) + (aa1.x + aa1.y);
        float s = 0.5f * x0s + (ssv.x + ssv.y);

        // ---- pack z to f16 pairs: lane p holds (z[2p+1] lo, z[2p] hi) ----
        int za = __builtin_amdgcn_ds_bpermute(((2 * lane) & 63) << 2,
                                              __float_as_int(zc));      // z[2p]
        int zb = __builtin_amdgcn_ds_bpermute(((2 * lane + 1) & 63) << 2,
                                              __float_as_int(zc));      // z[2p+1]
#if __has_builtin(__builtin_amdgcn_cvt_pkrtz)
        h2f vz = __builtin_bit_cast(h2f,
            __builtin_amdgcn_cvt_pkrtz(__int_as_float(zb), __int_as_float(za)));
#else
        h2f vz; vz.x = (_Float16)__int_as_float(zb); vz.y = (_Float16)__int_as_float(za);
#endif
        const int vzi = __builtin_bit_cast(int, vz);

        // ---- windowed IR -> f16, both copies; order pinned (cross-lane RAW,
        //      sched_barrier is correctness-critical per R6) ----
        __builtin_amdgcn_sched_barrier(0);
        {
            __half hA = __float2half(cA * a);   // tap 63-lane
            __half hB = __float2half(cB * a);   // tap 65+lane
            hE[127 - lane] = hA;  hE[129 + lane] = hB;
            hO[128 - lane] = hA;  hO[130 + lane] = hB;
            if (lane == 0) {                    // center tap 64
                __half hC = __float2half(c0 * s);
                hE[128] = hC;  hO[129] = hC;
            }
        }
        __builtin_amdgcn_sched_barrier(0);

        // ---- Phase B: 3 dword loads + 1 readlane + 3 dot2 per j-pair ----
        #pragma unroll
        for (int p = 0; p < 32; ++p) {
            const int pc = p & 1;
            int zs = __builtin_amdgcn_readlane(vzi, p);
            h2f z2 = __builtin_bit_cast(h2f, zs);
            h2f v0 = bmin[(31 - p)];        // seg0 (out k=lane)
            h2f v1 = bmin[(31 - p) + 32];   // seg1 (k=lane+64)
            h2f v2 = bmin[(31 - p) + 64];   // seg2 (k=lane+128)
            wa[pc] = FDOT2(v0, z2, wa[pc]);
            wb[pc] = FDOT2(v1, z2, wb[pc]);
            wc[pc] = FDOT2(v2, z2, wc[pc]);
        }
        __builtin_amdgcn_sched_barrier(0);   // WAR fence vs next frame's writes

        // ---- retire slot i (i<2 overlaps previous group -> atomic) ----
        float va = (wa[0] + wa[1]) * GAIN_;
        if (i < 2) atomicAdd(op, va); else *op = va;
        op += HOP_;
        wa[0] = wb[0]; wa[1] = wb[1];
        wb[0] = wc[0]; wb[1] = wc[1];
        wc[0] = 0.0f;  wc[1] = 0.0f;
        Xf += L_; Zf += HOP_;
    }
    atomicAdd(op,        (wa[0] + wa[1]) * GAIN_);  // slot 8 (next group's)
    atomicAdd(op + HOP_, (wb[0] + wb[1]) * GAIN_);  // slot 9
}

extern "C" void kernel_launch(void* const* d_in, const int* in_sizes, int n_in,
                              void* d_out, int out_size, void* d_ws, size_t ws_size,
                              hipStream_t stream) {
    const float* nfilt = (const float*)d_in[0];
    const float* noise = (const float*)d_in[1];
    float* out = (float*)d_out;

    hipMemsetAsync(d_out, 0, (size_t)out_size * sizeof(float), stream);

    dim3 grid(B_ * BLKS_PER_B_);   // 4000 blocks
    dim3 block(256);
    filtered_noise_kernel<<<grid, block, 0, stream>>>(nfilt, noise, out);
}